// Round 1
// baseline (406.287 us; speedup 1.0000x reference)
//
#include <hip/hip_runtime.h>
#include <hip/hip_bf16.h>

// GNN_LinearAttn: B=8, N=2048, D=512, fp32 in/out, bf16 MFMA internally.
//
// Pipeline:
//  K0 castw:   Wqk/Wl/Wr fp32 -> bf16
//  K1 gate:    deg=rowsum(adj); xg = x * sigmoid(deg*Wd + bd)      (bf16)
//  K2 transp:  xgT[b,d,n] = xg[b,n,d]                              (bf16)
//  K3 gemm:    QK = sigmoid(xg @ Wqk^T + bqk)                      (bf16)
//  K4 gemm:    S  = (QK @ QK^T) / sqrt(D) * adj                    (bf16)
//  K5 denom:   denom = rowsum(S) + 1e-6                            (fp32)
//  K6 gemm:    h  = (S @ xgT^T) / denom                            (bf16)
//  K7 gemm:    out = relu(h @ Wl^T + bl + xg @ Wr^T)               (fp32)
//
// All GEMMs are B^T-pattern (both operands row-major along K) -> one shared
// core: 128x128 block tile, BK=64, 4 waves each 64x64, 16x16x32 bf16 MFMA,
// global_load_lds width=16 staging with XOR-chunk swizzle (bank-conflict-free
// without padding, which global_load_lds forbids).

typedef __bf16 bf16;
typedef __bf16 bf16x8 __attribute__((ext_vector_type(8)));
typedef float  f32x4  __attribute__((ext_vector_type(4)));

#define Bb 8
#define Nn 2048
#define Dd 512

__device__ __forceinline__ bf16 to_bf16(float f) { return (bf16)f; }
__device__ __forceinline__ float sigmoidf_(float x) { return 1.0f / (1.0f + __expf(-x)); }

__device__ __forceinline__ void gld16(const void* g, void* l) {
    __builtin_amdgcn_global_load_lds(
        (__attribute__((address_space(1))) void*)(void*)g,
        (__attribute__((address_space(3))) void*)l,
        16, 0, 0);
}

// ---------------- shared B^T GEMM core ----------------
// A:  row-major [.., lda], pre-offset to block row tile (128 rows)
// Bt: row-major [.., ldb], pre-offset to block col tile (128 rows = out cols)
// Accumulates into acc[4][4] (each wave: 64x64 = 4x4 frags of 16x16).
// LDS layout: per tile 128 rows x 8 chunks of 16B; physical chunk slot =
// logical_chunk ^ (row & 7)  (XOR swizzle; staging picks matching gsrc chunk).
__device__ __forceinline__ void gemm_bt_core(
    const bf16* __restrict__ A, const bf16* __restrict__ Bt,
    int lda, int ldb, int K,
    char* As, char* Bs, f32x4 acc[4][4])
{
    const int tid  = threadIdx.x;
    const int lane = tid & 63;
    const int wave = tid >> 6;
    const int wm = (wave >> 1) << 6;
    const int wn = (wave & 1) << 6;

    for (int kt = 0; kt < K; kt += 64) {
#pragma unroll
        for (int i = 0; i < 4; ++i) {
            int ff   = i * 256 + tid;       // 0..1023 16B-chunks
            int row  = ff >> 3;             // 0..127
            int slot = ff & 7;              // physical slot
            int gch  = slot ^ (row & 7);    // logical (global) chunk
            gld16(A  + (size_t)row * lda + kt + gch * 8, As + ff * 16);
            gld16(Bt + (size_t)row * ldb + kt + gch * 8, Bs + ff * 16);
        }
        __syncthreads();
#pragma unroll
        for (int ks = 0; ks < 2; ++ks) {
            bf16x8 af[4], bfr[4];
#pragma unroll
            for (int mi = 0; mi < 4; ++mi) {
                int row  = wm + mi * 16 + (lane & 15);
                int slot = ((ks << 2) + (lane >> 4)) ^ (row & 7);
                af[mi] = *(const bf16x8*)(As + row * 128 + slot * 16);
            }
#pragma unroll
            for (int ni = 0; ni < 4; ++ni) {
                int row  = wn + ni * 16 + (lane & 15);
                int slot = ((ks << 2) + (lane >> 4)) ^ (row & 7);
                bfr[ni] = *(const bf16x8*)(Bs + row * 128 + slot * 16);
            }
#pragma unroll
            for (int mi = 0; mi < 4; ++mi)
#pragma unroll
                for (int ni = 0; ni < 4; ++ni)
                    acc[mi][ni] = __builtin_amdgcn_mfma_f32_16x16x32_bf16(
                        af[mi], bfr[ni], acc[mi][ni], 0, 0, 0);
        }
        __syncthreads();
    }
}

#define GEMM_PROLOGUE()                                  \
    __shared__ __align__(16) char As[16384];             \
    __shared__ __align__(16) char Bs[16384];             \
    f32x4 acc[4][4];                                     \
    _Pragma("unroll") for (int mi = 0; mi < 4; ++mi)     \
    _Pragma("unroll") for (int ni = 0; ni < 4; ++ni)     \
        acc[mi][ni] = (f32x4){0.f, 0.f, 0.f, 0.f};

#define GEMM_EPILOGUE_BEGIN()                            \
    const int lane = threadIdx.x & 63;                   \
    const int wave = threadIdx.x >> 6;                   \
    const int wm = (wave >> 1) << 6;                     \
    const int wn = (wave & 1) << 6;                      \
    const int cq = lane >> 4;                            \
    const int cl = lane & 15;                            \
    _Pragma("unroll") for (int mi = 0; mi < 4; ++mi)     \
    _Pragma("unroll") for (int ni = 0; ni < 4; ++ni)     \
    _Pragma("unroll") for (int r = 0; r < 4; ++r) {      \
        const int row = blockRow + wm + mi * 16 + cq * 4 + r; \
        const int col = blockCol + wn + ni * 16 + cl;    \
        float v = acc[mi][ni][r];

#define GEMM_EPILOGUE_END() }

// ---------------- K0: weight casts ----------------
__global__ __launch_bounds__(256) void k_castw(
    const float* __restrict__ Wqk, const float* __restrict__ Wl,
    const float* __restrict__ Wr,
    bf16* __restrict__ Wqkb, bf16* __restrict__ Wlb, bf16* __restrict__ Wrb)
{
    int i = blockIdx.x * 256 + threadIdx.x;   // 262144 total
    Wqkb[i] = to_bf16(Wqk[i]);
    Wlb[i]  = to_bf16(Wl[i]);
    Wrb[i]  = to_bf16(Wr[i]);
}

// ---------------- K1: deg + gate + xg ----------------
__global__ __launch_bounds__(256) void k_gate(
    const float* __restrict__ x, const float* __restrict__ adj,
    const float* __restrict__ Wd, const float* __restrict__ bd,
    bf16* __restrict__ xg)
{
    const int rowg = blockIdx.x;                   // b*N + n
    const float4* arow = (const float4*)(adj + (size_t)rowg * Nn);
    float4 v0 = arow[threadIdx.x];
    float4 v1 = arow[threadIdx.x + 256];
    float s = v0.x + v0.y + v0.z + v0.w + v1.x + v1.y + v1.z + v1.w;
#pragma unroll
    for (int off = 32; off > 0; off >>= 1) s += __shfl_down(s, off, 64);
    __shared__ float red[4];
    if ((threadIdx.x & 63) == 0) red[threadIdx.x >> 6] = s;
    __syncthreads();
    const float deg = red[0] + red[1] + red[2] + red[3];
#pragma unroll
    for (int d = threadIdx.x; d < Dd; d += 256) {
        float g = sigmoidf_(deg * Wd[d] + bd[d]);
        xg[(size_t)rowg * Dd + d] = to_bf16(x[(size_t)rowg * Dd + d] * g);
    }
}

// ---------------- K2: transpose xg -> xgT ----------------
__global__ __launch_bounds__(256) void k_transpose(
    const bf16* __restrict__ xg, bf16* __restrict__ xgT)
{
    const int b = blockIdx.z, nt = blockIdx.y, dt = blockIdx.x;
    __shared__ bf16 tile[64][66];                  // +2 pad: conflict-free
    const int c = threadIdx.x & 63, r0 = threadIdx.x >> 6;
    const bf16* src = xg + ((size_t)b * Nn + nt * 64) * Dd + dt * 64;
#pragma unroll
    for (int i = 0; i < 16; ++i) {
        int r = i * 4 + r0;
        tile[r][c] = src[(size_t)r * Dd + c];
    }
    __syncthreads();
    bf16* dst = xgT + ((size_t)b * Dd + dt * 64) * Nn + nt * 64;
#pragma unroll
    for (int i = 0; i < 16; ++i) {
        int r = i * 4 + r0;
        dst[(size_t)r * Nn + c] = tile[c][r];
    }
}

// ---------------- K3: QK = sigmoid(xg @ Wqk^T + bqk) ----------------
__global__ __launch_bounds__(256) void k_qk_gemm(
    const bf16* __restrict__ xg, const bf16* __restrict__ Wqkb,
    const float* __restrict__ bqk, bf16* __restrict__ QK)
{
    const int blockRow = blockIdx.y * 128;   // 0..16383 (B*N flattened)
    const int blockCol = blockIdx.x * 128;   // 0..511
    GEMM_PROLOGUE();
    gemm_bt_core(xg + (size_t)blockRow * Dd, Wqkb + (size_t)blockCol * Dd,
                 Dd, Dd, Dd, As, Bs, acc);
    GEMM_EPILOGUE_BEGIN();
    QK[(size_t)row * Dd + col] = to_bf16(sigmoidf_(v + bqk[col]));
    GEMM_EPILOGUE_END();
}

// ---------------- K4: S = (QK @ QK^T) * scale * adj ----------------
__global__ __launch_bounds__(256) void k_s_gemm(
    const bf16* __restrict__ QK, const float* __restrict__ adj,
    bf16* __restrict__ S)
{
    const int b = blockIdx.z;
    const int blockRow = blockIdx.y * 128;
    const int blockCol = blockIdx.x * 128;
    const bf16* Qb = QK + (size_t)b * Nn * Dd;
    GEMM_PROLOGUE();
    gemm_bt_core(Qb + (size_t)blockRow * Dd, Qb + (size_t)blockCol * Dd,
                 Dd, Dd, Dd, As, Bs, acc);
    const float scale = 0.044194173824159216f;  // 1/sqrt(512)
    GEMM_EPILOGUE_BEGIN();
    float a = adj[((size_t)b * Nn + row) * Nn + col];
    S[((size_t)b * Nn + row) * Nn + col] = to_bf16(v * scale * a);
    GEMM_EPILOGUE_END();
}

// ---------------- K5: denom = rowsum(S) + 1e-6 ----------------
__global__ __launch_bounds__(256) void k_denom(
    const bf16* __restrict__ S, float* __restrict__ denom)
{
    const int rowg = blockIdx.x;                 // b*N + i
    const bf16* p = S + (size_t)rowg * Nn;
    bf16x8 v = *(const bf16x8*)(p + threadIdx.x * 8);
    float s = 0.f;
#pragma unroll
    for (int j = 0; j < 8; ++j) s += (float)v[j];
#pragma unroll
    for (int off = 32; off > 0; off >>= 1) s += __shfl_down(s, off, 64);
    __shared__ float red[4];
    if ((threadIdx.x & 63) == 0) red[threadIdx.x >> 6] = s;
    __syncthreads();
    if (threadIdx.x == 0)
        denom[rowg] = red[0] + red[1] + red[2] + red[3] + 1e-6f;
}

// ---------------- K6: h = (S @ xgT^T) / denom ----------------
__global__ __launch_bounds__(256) void k_h_gemm(
    const bf16* __restrict__ S, const bf16* __restrict__ xgT,
    const float* __restrict__ denom, bf16* __restrict__ h)
{
    const int b = blockIdx.z;
    const int blockRow = blockIdx.y * 128;   // n: 0..2047
    const int blockCol = blockIdx.x * 128;   // d: 0..511
    GEMM_PROLOGUE();
    gemm_bt_core(S + ((size_t)b * Nn + blockRow) * Nn,
                 xgT + ((size_t)b * Dd + blockCol) * Nn,
                 Nn, Nn, Nn, As, Bs, acc);
    GEMM_EPILOGUE_BEGIN();
    float dn = denom[b * Nn + row];
    h[((size_t)b * Nn + row) * Dd + col] = to_bf16(v / dn);
    GEMM_EPILOGUE_END();
}

// ---------------- K7: out = relu(h @ Wl^T + bl + xg @ Wr^T) ----------------
__global__ __launch_bounds__(256) void k_out_gemm(
    const bf16* __restrict__ h, const bf16* __restrict__ xg,
    const bf16* __restrict__ Wlb, const bf16* __restrict__ Wrb,
    const float* __restrict__ bl, float* __restrict__ out)
{
    const int blockRow = blockIdx.y * 128;   // 0..16383
    const int blockCol = blockIdx.x * 128;   // 0..511
    GEMM_PROLOGUE();
    gemm_bt_core(h  + (size_t)blockRow * Dd, Wlb + (size_t)blockCol * Dd,
                 Dd, Dd, Dd, As, Bs, acc);
    gemm_bt_core(xg + (size_t)blockRow * Dd, Wrb + (size_t)blockCol * Dd,
                 Dd, Dd, Dd, As, Bs, acc);
    GEMM_EPILOGUE_BEGIN();
    float o = v + bl[col];
    out[(size_t)row * Dd + col] = fmaxf(o, 0.f);
    GEMM_EPILOGUE_END();
}

extern "C" void kernel_launch(void* const* d_in, const int* in_sizes, int n_in,
                              void* d_out, int out_size, void* d_ws, size_t ws_size,
                              hipStream_t stream) {
    const float* x   = (const float*)d_in[0];
    const float* adj = (const float*)d_in[1];
    const float* Wqk = (const float*)d_in[2];
    const float* bqk = (const float*)d_in[3];
    const float* Wl  = (const float*)d_in[4];
    const float* bl  = (const float*)d_in[5];
    const float* Wr  = (const float*)d_in[6];
    const float* Wd  = (const float*)d_in[7];
    const float* bd  = (const float*)d_in[8];
    float* out = (float*)d_out;

    // workspace carve (all regions fully rewritten every call; no zero-init needed)
    char* ws = (char*)d_ws;
    bf16* xg   = (bf16*)ws;  ws += (size_t)Bb * Nn * Dd * 2;   // 16.78 MB
    bf16* xgT  = (bf16*)ws;  ws += (size_t)Bb * Dd * Nn * 2;   // 16.78 MB
    bf16* QK   = (bf16*)ws;  ws += (size_t)Bb * Nn * Dd * 2;   // 16.78 MB
    bf16* S    = (bf16*)ws;  ws += (size_t)Bb * Nn * Nn * 2;   // 67.1 MB
    bf16* Wqkb = (bf16*)ws;  ws += (size_t)Dd * Dd * 2;
    bf16* Wlb  = (bf16*)ws;  ws += (size_t)Dd * Dd * 2;
    bf16* Wrb  = (bf16*)ws;  ws += (size_t)Dd * Dd * 2;
    float* denom = (float*)ws; ws += (size_t)Bb * Nn * 4;
    bf16* h = QK;   // QK is dead after K4/K5; alias h over it

    k_castw<<<dim3(1024), 256, 0, stream>>>(Wqk, Wl, Wr, Wqkb, Wlb, Wrb);
    k_gate<<<dim3(Bb * Nn), 256, 0, stream>>>(x, adj, Wd, bd, xg);
    k_transpose<<<dim3(Dd / 64, Nn / 64, Bb), 256, 0, stream>>>(xg, xgT);
    k_qk_gemm<<<dim3(Dd / 128, (Bb * Nn) / 128), 256, 0, stream>>>(xg, Wqkb, bqk, QK);
    k_s_gemm<<<dim3(Nn / 128, Nn / 128, Bb), 256, 0, stream>>>(QK, adj, S);
    k_denom<<<dim3(Bb * Nn), 256, 0, stream>>>(S, denom);
    k_h_gemm<<<dim3(Dd / 128, Nn / 128, Bb), 256, 0, stream>>>(S, xgT, denom, h);
    k_out_gemm<<<dim3(Dd / 128, (Bb * Nn) / 128), 256, 0, stream>>>(h, xg, Wlb, Wrb, bl, out);
}

// Round 2
// 404.646 us; speedup vs baseline: 1.0041x; 1.0041x over previous
//
#include <hip/hip_runtime.h>
#include <hip/hip_bf16.h>

// GNN_LinearAttn: B=8, N=2048, D=512, fp32 in/out, bf16 MFMA internally.
//
// Pipeline:
//  K0 castw:   Wqk/Wl/Wr fp32 -> bf16
//  K1 gate:    deg=rowsum(adj); xg = x * sigmoid(deg*Wd + bd)      (bf16)
//  K2 transp:  xgT[b,d,n] = xg[b,n,d]                              (bf16)
//  K3 gemm:    QK = sigmoid(xg @ Wqk^T + bqk)                      (bf16)
//  K4 gemm:    S  = (QK @ QK^T)/sqrt(D) * adj; denom += rowsum(S)  (bf16)
//  K5 gemm:    h  = (S @ xgT^T) / (denom+1e-6)                     (bf16)
//  K6 gemm:    out = relu(h @ Wl^T + bl + xg @ Wr^T)               (fp32)
//
// GEMM core: 128x128 block tile, BK=64, 4 waves each 64x64, 16x16x32 bf16
// MFMA, global_load_lds width=16 staging with XOR-chunk swizzle.
// Epilogues: LDS roundtrip (fp32, stride 132, two 64-row phases) so every
// lane owns 8 contiguous cols -> float4 adj/bias loads, bf16x8/float4 stores.

typedef __bf16 bf16;
typedef __bf16 bf16x8 __attribute__((ext_vector_type(8)));
typedef float  f32x4  __attribute__((ext_vector_type(4)));

#define Bb 8
#define Nn 2048
#define Dd 512
#define SMEM_BYTES 33792   // max(As+Bs=32768, epilogue 64*132*4=33792)

__device__ __forceinline__ bf16 to_bf16(float f) { return (bf16)f; }
__device__ __forceinline__ float sigmoidf_(float x) { return 1.0f / (1.0f + __expf(-x)); }

__device__ __forceinline__ void gld16(const void* g, void* l) {
    __builtin_amdgcn_global_load_lds(
        (__attribute__((address_space(1))) void*)(void*)g,
        (__attribute__((address_space(3))) void*)l,
        16, 0, 0);
}

// ---------------- shared B^T GEMM core ----------------
// A:  row-major [.., lda], pre-offset to block row tile (128 rows)
// Bt: row-major [.., ldb], pre-offset to block col tile (128 rows = out cols)
// LDS: per tile 128 rows x 8 chunks of 16B; phys slot = chunk ^ (row & 7).
__device__ __forceinline__ void gemm_bt_core(
    const bf16* __restrict__ A, const bf16* __restrict__ Bt,
    int lda, int ldb, int K,
    char* As, char* Bs, f32x4 acc[4][4])
{
    const int tid  = threadIdx.x;
    const int lane = tid & 63;
    const int wave = tid >> 6;
    const int wm = (wave >> 1) << 6;
    const int wn = (wave & 1) << 6;

    for (int kt = 0; kt < K; kt += 64) {
#pragma unroll
        for (int i = 0; i < 4; ++i) {
            int ff   = i * 256 + tid;       // 0..1023 16B-chunks
            int row  = ff >> 3;             // 0..127
            int slot = ff & 7;              // physical slot
            int gch  = slot ^ (row & 7);    // logical (global) chunk
            gld16(A  + (size_t)row * lda + kt + gch * 8, As + ff * 16);
            gld16(Bt + (size_t)row * ldb + kt + gch * 8, Bs + ff * 16);
        }
        __syncthreads();
#pragma unroll
        for (int ks = 0; ks < 2; ++ks) {
            bf16x8 af[4], bfr[4];
#pragma unroll
            for (int mi = 0; mi < 4; ++mi) {
                int row  = wm + mi * 16 + (lane & 15);
                int slot = ((ks << 2) + (lane >> 4)) ^ (row & 7);
                af[mi] = *(const bf16x8*)(As + row * 128 + slot * 16);
            }
#pragma unroll
            for (int ni = 0; ni < 4; ++ni) {
                int row  = wn + ni * 16 + (lane & 15);
                int slot = ((ks << 2) + (lane >> 4)) ^ (row & 7);
                bfr[ni] = *(const bf16x8*)(Bs + row * 128 + slot * 16);
            }
#pragma unroll
            for (int mi = 0; mi < 4; ++mi)
#pragma unroll
                for (int ni = 0; ni < 4; ++ni)
                    acc[mi][ni] = __builtin_amdgcn_mfma_f32_16x16x32_bf16(
                        af[mi], bfr[ni], acc[mi][ni], 0, 0, 0);
        }
        __syncthreads();
    }
}

#define GEMM_PROLOGUE()                                  \
    __shared__ __align__(16) char smem[SMEM_BYTES];      \
    char* As = smem;                                     \
    char* Bs = smem + 16384;                             \
    f32x4 acc[4][4];                                     \
    _Pragma("unroll") for (int mi = 0; mi < 4; ++mi)     \
    _Pragma("unroll") for (int ni = 0; ni < 4; ++ni)     \
        acc[mi][ni] = (f32x4){0.f, 0.f, 0.f, 0.f};

// LDS-roundtrip epilogue: acc (C/D frag layout) -> LDS fp32 [64][132] in two
// 64-row phases -> each thread reads 8 contiguous cols of 4 rows per phase.
// emit(row_local 0..127, col_local = 8-aligned, v[8]).
// Write pattern: banks 2-way (free); read float4: 8-cycle b128 floor.
template <typename F>
__device__ __forceinline__ void epilogue_rt(f32x4 acc[4][4], char* smem, F&& emit)
{
    const int tid  = threadIdx.x;
    const int lane = tid & 63;
    const int wave = tid >> 6;
    const int wm = (wave >> 1) << 6;
    const int wn = (wave & 1) << 6;
    const int cq = lane >> 4;
    const int cl = lane & 15;
    float* t = (float*)smem;         // [64][132]
    const int chunk = tid & 15;      // col chunk (8 f32)
    const int rbase = tid >> 4;      // 0..15
#pragma unroll
    for (int ph = 0; ph < 2; ++ph) {
        __syncthreads();
        if ((wm >> 6) == ph) {       // waves owning rows [ph*64, ph*64+64)
#pragma unroll
            for (int mi = 0; mi < 4; ++mi)
#pragma unroll
                for (int ni = 0; ni < 4; ++ni)
#pragma unroll
                    for (int r = 0; r < 4; ++r) {
                        int lr = mi * 16 + cq * 4 + r;   // 0..63 within phase
                        int lc = wn + ni * 16 + cl;
                        t[lr * 132 + lc] = acc[mi][ni][r];
                    }
        }
        __syncthreads();
#pragma unroll
        for (int rr = 0; rr < 4; ++rr) {
            int lr = rr * 16 + rbase;
            f32x4 a = *(const f32x4*)&t[lr * 132 + chunk * 8];
            f32x4 b = *(const f32x4*)&t[lr * 132 + chunk * 8 + 4];
            float v[8] = {a[0], a[1], a[2], a[3], b[0], b[1], b[2], b[3]};
            emit(ph * 64 + lr, chunk * 8, v);
        }
    }
}

// ---------------- K0: weight casts ----------------
__global__ __launch_bounds__(256) void k_castw(
    const float* __restrict__ Wqk, const float* __restrict__ Wl,
    const float* __restrict__ Wr,
    bf16* __restrict__ Wqkb, bf16* __restrict__ Wlb, bf16* __restrict__ Wrb)
{
    int i = blockIdx.x * 256 + threadIdx.x;   // 262144 total
    Wqkb[i] = to_bf16(Wqk[i]);
    Wlb[i]  = to_bf16(Wl[i]);
    Wrb[i]  = to_bf16(Wr[i]);
}

// ---------------- K1: deg + gate + xg ----------------
__global__ __launch_bounds__(256) void k_gate(
    const float* __restrict__ x, const float* __restrict__ adj,
    const float* __restrict__ Wd, const float* __restrict__ bd,
    bf16* __restrict__ xg)
{
    const int rowg = blockIdx.x;                   // b*N + n
    const float4* arow = (const float4*)(adj + (size_t)rowg * Nn);
    float4 v0 = arow[threadIdx.x];
    float4 v1 = arow[threadIdx.x + 256];
    float s = v0.x + v0.y + v0.z + v0.w + v1.x + v1.y + v1.z + v1.w;
#pragma unroll
    for (int off = 32; off > 0; off >>= 1) s += __shfl_down(s, off, 64);
    __shared__ float red[4];
    if ((threadIdx.x & 63) == 0) red[threadIdx.x >> 6] = s;
    __syncthreads();
    const float deg = red[0] + red[1] + red[2] + red[3];
#pragma unroll
    for (int d = threadIdx.x; d < Dd; d += 256) {
        float g = sigmoidf_(deg * Wd[d] + bd[d]);
        xg[(size_t)rowg * Dd + d] = to_bf16(x[(size_t)rowg * Dd + d] * g);
    }
}

// ---------------- K2: transpose xg -> xgT ----------------
__global__ __launch_bounds__(256) void k_transpose(
    const bf16* __restrict__ xg, bf16* __restrict__ xgT)
{
    const int b = blockIdx.z, nt = blockIdx.y, dt = blockIdx.x;
    __shared__ bf16 tile[64][66];
    const int c = threadIdx.x & 63, r0 = threadIdx.x >> 6;
    const bf16* src = xg + ((size_t)b * Nn + nt * 64) * Dd + dt * 64;
#pragma unroll
    for (int i = 0; i < 16; ++i) {
        int r = i * 4 + r0;
        tile[r][c] = src[(size_t)r * Dd + c];
    }
    __syncthreads();
    bf16* dst = xgT + ((size_t)b * Dd + dt * 64) * Nn + nt * 64;
#pragma unroll
    for (int i = 0; i < 16; ++i) {
        int r = i * 4 + r0;
        dst[(size_t)r * Nn + c] = tile[c][r];
    }
}

// ---------------- K3: QK = sigmoid(xg @ Wqk^T + bqk) ----------------
__global__ __launch_bounds__(256) void k_qk_gemm(
    const bf16* __restrict__ xg, const bf16* __restrict__ Wqkb,
    const float* __restrict__ bqk, bf16* __restrict__ QK)
{
    const int blockRow = blockIdx.y * 128;   // 0..16383 (B*N flattened)
    const int blockCol = blockIdx.x * 128;   // 0..511
    GEMM_PROLOGUE();
    gemm_bt_core(xg + (size_t)blockRow * Dd, Wqkb + (size_t)blockCol * Dd,
                 Dd, Dd, Dd, As, Bs, acc);
    epilogue_rt(acc, smem, [&](int lr, int lc, float* v) {
        int c = blockCol + lc;
        float4 b0 = *(const float4*)(bqk + c);
        float4 b1 = *(const float4*)(bqk + c + 4);
        float bb[8] = {b0.x, b0.y, b0.z, b0.w, b1.x, b1.y, b1.z, b1.w};
        bf16x8 o;
#pragma unroll
        for (int j = 0; j < 8; ++j) o[j] = to_bf16(sigmoidf_(v[j] + bb[j]));
        *(bf16x8*)(QK + (size_t)(blockRow + lr) * Dd + c) = o;
    });
}

// ------- K4: S = (QK @ QK^T) * scale * adj, denom += rowsum(S) -------
__global__ __launch_bounds__(256) void k_s_gemm(
    const bf16* __restrict__ QK, const float* __restrict__ adj,
    bf16* __restrict__ S, float* __restrict__ denom)
{
    const int b = blockIdx.z;
    const int blockRow = blockIdx.y * 128;
    const int blockCol = blockIdx.x * 128;
    const bf16* Qb = QK + (size_t)b * Nn * Dd;
    GEMM_PROLOGUE();
    gemm_bt_core(Qb + (size_t)blockRow * Dd, Qb + (size_t)blockCol * Dd,
                 Dd, Dd, Dd, As, Bs, acc);
    const float scale = 0.044194173824159216f;  // 1/sqrt(512)
    epilogue_rt(acc, smem, [&](int lr, int lc, float* v) {
        int gRow = blockRow + lr;
        size_t base = ((size_t)b * Nn + gRow) * Nn + blockCol + lc;
        float4 a0 = *(const float4*)(adj + base);
        float4 a1 = *(const float4*)(adj + base + 4);
        float aa[8] = {a0.x, a0.y, a0.z, a0.w, a1.x, a1.y, a1.z, a1.w};
        bf16x8 o;
        float ds = 0.f;
#pragma unroll
        for (int j = 0; j < 8; ++j) {
            float s = v[j] * scale * aa[j];
            bf16 sb = to_bf16(s);
            o[j] = sb;
            ds += (float)sb;     // sum the rounded value (matches h_gemm input)
        }
        *(bf16x8*)(S + base) = o;
#pragma unroll
        for (int off = 8; off > 0; off >>= 1) ds += __shfl_xor(ds, off, 16);
        if ((threadIdx.x & 15) == 0) atomicAdd(&denom[b * Nn + gRow], ds);
    });
}

// ---------------- K5: h = (S @ xgT^T) / (denom + 1e-6) ----------------
__global__ __launch_bounds__(256) void k_h_gemm(
    const bf16* __restrict__ S, const bf16* __restrict__ xgT,
    const float* __restrict__ denom, bf16* __restrict__ h)
{
    const int b = blockIdx.z;
    const int blockRow = blockIdx.y * 128;   // n: 0..2047
    const int blockCol = blockIdx.x * 128;   // d: 0..511
    GEMM_PROLOGUE();
    gemm_bt_core(S + ((size_t)b * Nn + blockRow) * Nn,
                 xgT + ((size_t)b * Dd + blockCol) * Nn,
                 Nn, Nn, Nn, As, Bs, acc);
    epilogue_rt(acc, smem, [&](int lr, int lc, float* v) {
        int gRow = blockRow + lr;
        float inv = 1.0f / (denom[b * Nn + gRow] + 1e-6f);
        bf16x8 o;
#pragma unroll
        for (int j = 0; j < 8; ++j) o[j] = to_bf16(v[j] * inv);
        *(bf16x8*)(h + ((size_t)b * Nn + gRow) * Dd + blockCol + lc) = o;
    });
}

// ---------------- K6: out = relu(h @ Wl^T + bl + xg @ Wr^T) ----------------
__global__ __launch_bounds__(256) void k_out_gemm(
    const bf16* __restrict__ h, const bf16* __restrict__ xg,
    const bf16* __restrict__ Wlb, const bf16* __restrict__ Wrb,
    const float* __restrict__ bl, float* __restrict__ out)
{
    const int blockRow = blockIdx.y * 128;   // 0..16383
    const int blockCol = blockIdx.x * 128;   // 0..511
    GEMM_PROLOGUE();
    gemm_bt_core(h  + (size_t)blockRow * Dd, Wlb + (size_t)blockCol * Dd,
                 Dd, Dd, Dd, As, Bs, acc);
    gemm_bt_core(xg + (size_t)blockRow * Dd, Wrb + (size_t)blockCol * Dd,
                 Dd, Dd, Dd, As, Bs, acc);
    epilogue_rt(acc, smem, [&](int lr, int lc, float* v) {
        int c = blockCol + lc;
        float4 b0 = *(const float4*)(bl + c);
        float4 b1 = *(const float4*)(bl + c + 4);
        float bb[8] = {b0.x, b0.y, b0.z, b0.w, b1.x, b1.y, b1.z, b1.w};
        float4 o0, o1;
        o0.x = fmaxf(v[0] + bb[0], 0.f); o0.y = fmaxf(v[1] + bb[1], 0.f);
        o0.z = fmaxf(v[2] + bb[2], 0.f); o0.w = fmaxf(v[3] + bb[3], 0.f);
        o1.x = fmaxf(v[4] + bb[4], 0.f); o1.y = fmaxf(v[5] + bb[5], 0.f);
        o1.z = fmaxf(v[6] + bb[6], 0.f); o1.w = fmaxf(v[7] + bb[7], 0.f);
        float* p = out + (size_t)(blockRow + lr) * Dd + c;
        *(float4*)p = o0;
        *(float4*)(p + 4) = o1;
    });
}

extern "C" void kernel_launch(void* const* d_in, const int* in_sizes, int n_in,
                              void* d_out, int out_size, void* d_ws, size_t ws_size,
                              hipStream_t stream) {
    const float* x   = (const float*)d_in[0];
    const float* adj = (const float*)d_in[1];
    const float* Wqk = (const float*)d_in[2];
    const float* bqk = (const float*)d_in[3];
    const float* Wl  = (const float*)d_in[4];
    const float* bl  = (const float*)d_in[5];
    const float* Wr  = (const float*)d_in[6];
    const float* Wd  = (const float*)d_in[7];
    const float* bd  = (const float*)d_in[8];
    float* out = (float*)d_out;

    char* ws = (char*)d_ws;
    bf16* xg   = (bf16*)ws;  ws += (size_t)Bb * Nn * Dd * 2;   // 16.78 MB
    bf16* xgT  = (bf16*)ws;  ws += (size_t)Bb * Dd * Nn * 2;   // 16.78 MB
    bf16* QK   = (bf16*)ws;  ws += (size_t)Bb * Nn * Dd * 2;   // 16.78 MB
    bf16* S    = (bf16*)ws;  ws += (size_t)Bb * Nn * Nn * 2;   // 67.1 MB
    bf16* Wqkb = (bf16*)ws;  ws += (size_t)Dd * Dd * 2;
    bf16* Wlb  = (bf16*)ws;  ws += (size_t)Dd * Dd * 2;
    bf16* Wrb  = (bf16*)ws;  ws += (size_t)Dd * Dd * 2;
    float* denom = (float*)ws; ws += (size_t)Bb * Nn * 4;
    bf16* h = QK;   // QK dead after K4; alias h over it

    hipMemsetAsync(denom, 0, (size_t)Bb * Nn * sizeof(float), stream);
    k_castw<<<dim3(1024), 256, 0, stream>>>(Wqk, Wl, Wr, Wqkb, Wlb, Wrb);
    k_gate<<<dim3(Bb * Nn), 256, 0, stream>>>(x, adj, Wd, bd, xg);
    k_transpose<<<dim3(Dd / 64, Nn / 64, Bb), 256, 0, stream>>>(xg, xgT);
    k_qk_gemm<<<dim3(Dd / 128, (Bb * Nn) / 128), 256, 0, stream>>>(xg, Wqkb, bqk, QK);
    k_s_gemm<<<dim3(Nn / 128, Nn / 128, Bb), 256, 0, stream>>>(QK, adj, S, denom);
    k_h_gemm<<<dim3(Dd / 128, Nn / 128, Bb), 256, 0, stream>>>(S, xgT, denom, h);
    k_out_gemm<<<dim3(Dd / 128, (Bb * Nn) / 128), 256, 0, stream>>>(h, xg, Wlb, Wrb, bl, out);
}

// Round 3
// 388.851 us; speedup vs baseline: 1.0448x; 1.0406x over previous
//
#include <hip/hip_runtime.h>
#include <hip/hip_bf16.h>

// GNN_LinearAttn: B=8, N=2048, D=512, fp32 in/out, bf16 MFMA internally.
//
// Pipeline:
//  K0 castw:   Wqk/Wl/Wr fp32 -> bf16
//  K1 gate:    deg=rowsum(adj); xg = x * sigmoid(deg*Wd + bd)      (bf16)
//  K2 transp:  xgT[b,d,n] = xg[b,n,d]                              (bf16)
//  K3 gemm:    QK = sigmoid(xg @ Wqk^T + bqk)                      (bf16)
//  K4 gemm:    S  = (QK @ QK^T)/sqrt(D) * adj; denom += rowsum(S)  (bf16)
//              -- SYMMETRIC: only 136 upper-tri block pairs computed;
//                 off-diag blocks emit both S[i,j] and S[j,i] (= T^T * adj)
//  K5 gemm:    h  = (S @ xgT^T) / (denom+1e-6)   [XCD-swizzled grid] (bf16)
//  K6 gemm:    out = relu(h @ Wl^T + bl + xg @ Wr^T)               (fp32)
//
// GEMM core: 128x128 block tile, BK=64, 4 waves each 64x64, 16x16x32 bf16
// MFMA, global_load_lds width=16 staging with XOR-chunk swizzle.
// Epilogues: LDS roundtrip (fp32, stride 132, two 64-row phases) so every
// lane owns 8 contiguous cols -> float4 adj/bias loads, bf16x8/float4 stores.

typedef __bf16 bf16;
typedef __bf16 bf16x8 __attribute__((ext_vector_type(8)));
typedef float  f32x4  __attribute__((ext_vector_type(4)));

#define Bb 8
#define Nn 2048
#define Dd 512
#define SMEM_BYTES 33792   // max(As+Bs=32768, epilogue 64*132*4=33792)

__device__ __forceinline__ bf16 to_bf16(float f) { return (bf16)f; }
__device__ __forceinline__ float sigmoidf_(float x) { return 1.0f / (1.0f + __expf(-x)); }

__device__ __forceinline__ void gld16(const void* g, void* l) {
    __builtin_amdgcn_global_load_lds(
        (__attribute__((address_space(1))) void*)(void*)g,
        (__attribute__((address_space(3))) void*)l,
        16, 0, 0);
}

// ---------------- shared B^T GEMM core ----------------
// A:  row-major [.., lda], pre-offset to block row tile (128 rows)
// Bt: row-major [.., ldb], pre-offset to block col tile (128 rows = out cols)
// LDS: per tile 128 rows x 8 chunks of 16B; phys slot = chunk ^ (row & 7).
__device__ __forceinline__ void gemm_bt_core(
    const bf16* __restrict__ A, const bf16* __restrict__ Bt,
    int lda, int ldb, int K,
    char* As, char* Bs, f32x4 acc[4][4])
{
    const int tid  = threadIdx.x;
    const int lane = tid & 63;
    const int wave = tid >> 6;
    const int wm = (wave >> 1) << 6;
    const int wn = (wave & 1) << 6;

    for (int kt = 0; kt < K; kt += 64) {
#pragma unroll
        for (int i = 0; i < 4; ++i) {
            int ff   = i * 256 + tid;       // 0..1023 16B-chunks
            int row  = ff >> 3;             // 0..127
            int slot = ff & 7;              // physical slot
            int gch  = slot ^ (row & 7);    // logical (global) chunk
            gld16(A  + (size_t)row * lda + kt + gch * 8, As + ff * 16);
            gld16(Bt + (size_t)row * ldb + kt + gch * 8, Bs + ff * 16);
        }
        __syncthreads();
#pragma unroll
        for (int ks = 0; ks < 2; ++ks) {
            bf16x8 af[4], bfr[4];
#pragma unroll
            for (int mi = 0; mi < 4; ++mi) {
                int row  = wm + mi * 16 + (lane & 15);
                int slot = ((ks << 2) + (lane >> 4)) ^ (row & 7);
                af[mi] = *(const bf16x8*)(As + row * 128 + slot * 16);
            }
#pragma unroll
            for (int ni = 0; ni < 4; ++ni) {
                int row  = wn + ni * 16 + (lane & 15);
                int slot = ((ks << 2) + (lane >> 4)) ^ (row & 7);
                bfr[ni] = *(const bf16x8*)(Bs + row * 128 + slot * 16);
            }
#pragma unroll
            for (int mi = 0; mi < 4; ++mi)
#pragma unroll
                for (int ni = 0; ni < 4; ++ni)
                    acc[mi][ni] = __builtin_amdgcn_mfma_f32_16x16x32_bf16(
                        af[mi], bfr[ni], acc[mi][ni], 0, 0, 0);
        }
        __syncthreads();
    }
}

#define GEMM_PROLOGUE()                                  \
    __shared__ __align__(16) char smem[SMEM_BYTES];      \
    char* As = smem;                                     \
    char* Bs = smem + 16384;                             \
    f32x4 acc[4][4];                                     \
    _Pragma("unroll") for (int mi = 0; mi < 4; ++mi)     \
    _Pragma("unroll") for (int ni = 0; ni < 4; ++ni)     \
        acc[mi][ni] = (f32x4){0.f, 0.f, 0.f, 0.f};

// LDS-roundtrip epilogue: acc (C/D frag layout) -> LDS fp32 [64][132] in two
// 64-row phases -> each thread reads 8 contiguous cols of 4 rows per phase.
template <typename F>
__device__ __forceinline__ void epilogue_rt(f32x4 acc[4][4], char* smem, F&& emit)
{
    const int tid  = threadIdx.x;
    const int lane = tid & 63;
    const int wave = tid >> 6;
    const int wm = (wave >> 1) << 6;
    const int wn = (wave & 1) << 6;
    const int cq = lane >> 4;
    const int cl = lane & 15;
    float* t = (float*)smem;         // [64][132]
    const int chunk = tid & 15;      // col chunk (8 f32)
    const int rbase = tid >> 4;      // 0..15
#pragma unroll
    for (int ph = 0; ph < 2; ++ph) {
        __syncthreads();
        if ((wm >> 6) == ph) {
#pragma unroll
            for (int mi = 0; mi < 4; ++mi)
#pragma unroll
                for (int ni = 0; ni < 4; ++ni)
#pragma unroll
                    for (int r = 0; r < 4; ++r) {
                        int lr = mi * 16 + cq * 4 + r;
                        int lc = wn + ni * 16 + cl;
                        t[lr * 132 + lc] = acc[mi][ni][r];
                    }
        }
        __syncthreads();
#pragma unroll
        for (int rr = 0; rr < 4; ++rr) {
            int lr = rr * 16 + rbase;
            f32x4 a = *(const f32x4*)&t[lr * 132 + chunk * 8];
            f32x4 b = *(const f32x4*)&t[lr * 132 + chunk * 8 + 4];
            float v[8] = {a[0], a[1], a[2], a[3], b[0], b[1], b[2], b[3]};
            emit(ph * 64 + lr, chunk * 8, v);
        }
    }
}

// ---------------- K0: weight casts ----------------
__global__ __launch_bounds__(256) void k_castw(
    const float* __restrict__ Wqk, const float* __restrict__ Wl,
    const float* __restrict__ Wr,
    bf16* __restrict__ Wqkb, bf16* __restrict__ Wlb, bf16* __restrict__ Wrb)
{
    int i = blockIdx.x * 256 + threadIdx.x;   // 262144 total
    Wqkb[i] = to_bf16(Wqk[i]);
    Wlb[i]  = to_bf16(Wl[i]);
    Wrb[i]  = to_bf16(Wr[i]);
}

// ---------------- K1: deg + gate + xg ----------------
__global__ __launch_bounds__(256) void k_gate(
    const float* __restrict__ x, const float* __restrict__ adj,
    const float* __restrict__ Wd, const float* __restrict__ bd,
    bf16* __restrict__ xg)
{
    const int rowg = blockIdx.x;                   // b*N + n
    const float4* arow = (const float4*)(adj + (size_t)rowg * Nn);
    float4 v0 = arow[threadIdx.x];
    float4 v1 = arow[threadIdx.x + 256];
    float s = v0.x + v0.y + v0.z + v0.w + v1.x + v1.y + v1.z + v1.w;
#pragma unroll
    for (int off = 32; off > 0; off >>= 1) s += __shfl_down(s, off, 64);
    __shared__ float red[4];
    if ((threadIdx.x & 63) == 0) red[threadIdx.x >> 6] = s;
    __syncthreads();
    const float deg = red[0] + red[1] + red[2] + red[3];
#pragma unroll
    for (int d = threadIdx.x; d < Dd; d += 256) {
        float g = sigmoidf_(deg * Wd[d] + bd[d]);
        xg[(size_t)rowg * Dd + d] = to_bf16(x[(size_t)rowg * Dd + d] * g);
    }
}

// ---------------- K2: transpose xg -> xgT ----------------
__global__ __launch_bounds__(256) void k_transpose(
    const bf16* __restrict__ xg, bf16* __restrict__ xgT)
{
    const int b = blockIdx.z, nt = blockIdx.y, dt = blockIdx.x;
    __shared__ bf16 tile[64][66];
    const int c = threadIdx.x & 63, r0 = threadIdx.x >> 6;
    const bf16* src = xg + ((size_t)b * Nn + nt * 64) * Dd + dt * 64;
#pragma unroll
    for (int i = 0; i < 16; ++i) {
        int r = i * 4 + r0;
        tile[r][c] = src[(size_t)r * Dd + c];
    }
    __syncthreads();
    bf16* dst = xgT + ((size_t)b * Dd + dt * 64) * Nn + nt * 64;
#pragma unroll
    for (int i = 0; i < 16; ++i) {
        int r = i * 4 + r0;
        dst[(size_t)r * Nn + c] = tile[c][r];
    }
}

// ---------------- K3: QK = sigmoid(xg @ Wqk^T + bqk) ----------------
__global__ __launch_bounds__(256) void k_qk_gemm(
    const bf16* __restrict__ xg, const bf16* __restrict__ Wqkb,
    const float* __restrict__ bqk, bf16* __restrict__ QK)
{
    const int blockRow = blockIdx.y * 128;   // 0..16383 (B*N flattened)
    const int blockCol = blockIdx.x * 128;   // 0..511
    GEMM_PROLOGUE();
    gemm_bt_core(xg + (size_t)blockRow * Dd, Wqkb + (size_t)blockCol * Dd,
                 Dd, Dd, Dd, As, Bs, acc);
    epilogue_rt(acc, smem, [&](int lr, int lc, float* v) {
        int c = blockCol + lc;
        float4 b0 = *(const float4*)(bqk + c);
        float4 b1 = *(const float4*)(bqk + c + 4);
        float bb[8] = {b0.x, b0.y, b0.z, b0.w, b1.x, b1.y, b1.z, b1.w};
        bf16x8 o;
#pragma unroll
        for (int j = 0; j < 8; ++j) o[j] = to_bf16(sigmoidf_(v[j] + bb[j]));
        *(bf16x8*)(QK + (size_t)(blockRow + lr) * Dd + c) = o;
    });
}

// ------- K4: S = (QK @ QK^T) * scale * adj, denom += rowsum(S) -------
// Symmetric: grid.x = 136 upper-tri block pairs (i<=j). T = QKi @ QKj^T is
// computed once; off-diag blocks write S[i,j] (normal) and S[j,i] (T^T).
__global__ __launch_bounds__(256) void k_s_gemm(
    const bf16* __restrict__ QK, const float* __restrict__ adj,
    bf16* __restrict__ S, float* __restrict__ denom)
{
    const int b = blockIdx.y;
    int t = blockIdx.x, i = 0;
    while (t >= 16 - i) { t -= 16 - i; ++i; }   // triangular decode, i<=j
    const int j = i + t;
    const int rowI = i * 128, rowJ = j * 128;
    const bf16* Qb = QK + (size_t)b * Nn * Dd;
    GEMM_PROLOGUE();
    gemm_bt_core(Qb + (size_t)rowI * Dd, Qb + (size_t)rowJ * Dd,
                 Dd, Dd, Dd, As, Bs, acc);
    const float scale = 0.044194173824159216f;  // 1/sqrt(512)

    const int tid  = threadIdx.x;
    const int lane = tid & 63;
    const int wave = tid >> 6;
    const int wm = (wave >> 1) << 6;
    const int wn = (wave & 1) << 6;
    const int cq = lane >> 4;
    const int cl = lane & 15;
    float* tls = (float*)smem;       // [64][132]
    const int chunk = tid & 15;
    const int rbase = tid >> 4;

    auto store_side = [&](int blockRow, int blockCol, bool trans) {
#pragma unroll
        for (int ph = 0; ph < 2; ++ph) {
            __syncthreads();
            if (!trans) {
                // phase ph owns OUT rows [ph*64, ph*64+64) = waves (wave>>1)==ph
                if ((wave >> 1) == ph) {
#pragma unroll
                    for (int mi = 0; mi < 4; ++mi)
#pragma unroll
                        for (int ni = 0; ni < 4; ++ni)
#pragma unroll
                            for (int r = 0; r < 4; ++r)
                                tls[(mi * 16 + cq * 4 + r) * 132 + wn + ni * 16 + cl]
                                    = acc[mi][ni][r];
                }
            } else {
                // transposed: OUT rows = T cols; phase ph cols owned by (wave&1)==ph
                if ((wave & 1) == ph) {
#pragma unroll
                    for (int mi = 0; mi < 4; ++mi)
#pragma unroll
                        for (int ni = 0; ni < 4; ++ni)
#pragma unroll
                            for (int r = 0; r < 4; ++r)
                                tls[(ni * 16 + cl) * 132 + wm + mi * 16 + cq * 4 + r]
                                    = acc[mi][ni][r];
                }
            }
            __syncthreads();
#pragma unroll
            for (int rr = 0; rr < 4; ++rr) {
                int lr = rr * 16 + rbase;
                f32x4 a = *(const f32x4*)&tls[lr * 132 + chunk * 8];
                f32x4 c4 = *(const f32x4*)&tls[lr * 132 + chunk * 8 + 4];
                float v[8] = {a[0], a[1], a[2], a[3], c4[0], c4[1], c4[2], c4[3]};
                int gRow = blockRow + ph * 64 + lr;
                size_t base = ((size_t)b * Nn + gRow) * Nn + blockCol + chunk * 8;
                float4 a0 = *(const float4*)(adj + base);
                float4 a1 = *(const float4*)(adj + base + 4);
                float aa[8] = {a0.x, a0.y, a0.z, a0.w, a1.x, a1.y, a1.z, a1.w};
                bf16x8 o;
                float ds = 0.f;
#pragma unroll
                for (int jj = 0; jj < 8; ++jj) {
                    float s = v[jj] * scale * aa[jj];
                    bf16 sb = to_bf16(s);
                    o[jj] = sb;
                    ds += (float)sb;   // sum rounded value (matches k_h input)
                }
                *(bf16x8*)(S + base) = o;
#pragma unroll
                for (int off = 8; off > 0; off >>= 1) ds += __shfl_xor(ds, off, 16);
                if ((tid & 15) == 0) atomicAdd(&denom[b * Nn + gRow], ds);
            }
        }
    };
    store_side(rowI, rowJ, false);
    if (i != j) store_side(rowJ, rowI, true);
}

// ---------------- K5: h = (S @ xgT^T) / (denom + 1e-6) ----------------
// XCD-swizzled 1-D grid: the 4 d-tiles of one row-group land on one XCD
// (assumes round-robin dispatch->XCD; perf heuristic only).
__global__ __launch_bounds__(256) void k_h_gemm(
    const bf16* __restrict__ S, const bf16* __restrict__ xgT,
    const float* __restrict__ denom, bf16* __restrict__ h)
{
    const int id  = blockIdx.x;          // 0..511
    const int xcd = id & 7;
    const int pos = id >> 3;             // 0..63
    const int xt  = pos & 3;             // d-tile
    const int rg  = xcd * 16 + (pos >> 2); // row-group 0..127
    const int b   = rg >> 4;
    const int blockRow = (rg & 15) * 128;
    const int blockCol = xt * 128;
    GEMM_PROLOGUE();
    gemm_bt_core(S + ((size_t)b * Nn + blockRow) * Nn,
                 xgT + ((size_t)b * Dd + blockCol) * Nn,
                 Nn, Nn, Nn, As, Bs, acc);
    epilogue_rt(acc, smem, [&](int lr, int lc, float* v) {
        int gRow = blockRow + lr;
        float inv = 1.0f / (denom[b * Nn + gRow] + 1e-6f);
        bf16x8 o;
#pragma unroll
        for (int j = 0; j < 8; ++j) o[j] = to_bf16(v[j] * inv);
        *(bf16x8*)(h + ((size_t)b * Nn + gRow) * Dd + blockCol + lc) = o;
    });
}

// ---------------- K6: out = relu(h @ Wl^T + bl + xg @ Wr^T) ----------------
__global__ __launch_bounds__(256) void k_out_gemm(
    const bf16* __restrict__ h, const bf16* __restrict__ xg,
    const bf16* __restrict__ Wlb, const bf16* __restrict__ Wrb,
    const float* __restrict__ bl, float* __restrict__ out)
{
    const int blockRow = blockIdx.y * 128;   // 0..16383
    const int blockCol = blockIdx.x * 128;   // 0..511
    GEMM_PROLOGUE();
    gemm_bt_core(h  + (size_t)blockRow * Dd, Wlb + (size_t)blockCol * Dd,
                 Dd, Dd, Dd, As, Bs, acc);
    gemm_bt_core(xg + (size_t)blockRow * Dd, Wrb + (size_t)blockCol * Dd,
                 Dd, Dd, Dd, As, Bs, acc);
    epilogue_rt(acc, smem, [&](int lr, int lc, float* v) {
        int c = blockCol + lc;
        float4 b0 = *(const float4*)(bl + c);
        float4 b1 = *(const float4*)(bl + c + 4);
        float bb[8] = {b0.x, b0.y, b0.z, b0.w, b1.x, b1.y, b1.z, b1.w};
        float4 o0, o1;
        o0.x = fmaxf(v[0] + bb[0], 0.f); o0.y = fmaxf(v[1] + bb[1], 0.f);
        o0.z = fmaxf(v[2] + bb[2], 0.f); o0.w = fmaxf(v[3] + bb[3], 0.f);
        o1.x = fmaxf(v[4] + bb[4], 0.f); o1.y = fmaxf(v[5] + bb[5], 0.f);
        o1.z = fmaxf(v[6] + bb[6], 0.f); o1.w = fmaxf(v[7] + bb[7], 0.f);
        float* p = out + (size_t)(blockRow + lr) * Dd + c;
        *(float4*)p = o0;
        *(float4*)(p + 4) = o1;
    });
}

extern "C" void kernel_launch(void* const* d_in, const int* in_sizes, int n_in,
                              void* d_out, int out_size, void* d_ws, size_t ws_size,
                              hipStream_t stream) {
    const float* x   = (const float*)d_in[0];
    const float* adj = (const float*)d_in[1];
    const float* Wqk = (const float*)d_in[2];
    const float* bqk = (const float*)d_in[3];
    const float* Wl  = (const float*)d_in[4];
    const float* bl  = (const float*)d_in[5];
    const float* Wr  = (const float*)d_in[6];
    const float* Wd  = (const float*)d_in[7];
    const float* bd  = (const float*)d_in[8];
    float* out = (float*)d_out;

    char* ws = (char*)d_ws;
    bf16* xg   = (bf16*)ws;  ws += (size_t)Bb * Nn * Dd * 2;   // 16.78 MB
    bf16* xgT  = (bf16*)ws;  ws += (size_t)Bb * Dd * Nn * 2;   // 16.78 MB
    bf16* QK   = (bf16*)ws;  ws += (size_t)Bb * Nn * Dd * 2;   // 16.78 MB
    bf16* S    = (bf16*)ws;  ws += (size_t)Bb * Nn * Nn * 2;   // 67.1 MB
    bf16* Wqkb = (bf16*)ws;  ws += (size_t)Dd * Dd * 2;
    bf16* Wlb  = (bf16*)ws;  ws += (size_t)Dd * Dd * 2;
    bf16* Wrb  = (bf16*)ws;  ws += (size_t)Dd * Dd * 2;
    float* denom = (float*)ws; ws += (size_t)Bb * Nn * 4;
    bf16* h = QK;   // QK dead after K4; alias h over it

    hipMemsetAsync(denom, 0, (size_t)Bb * Nn * sizeof(float), stream);
    k_castw<<<dim3(1024), 256, 0, stream>>>(Wqk, Wl, Wr, Wqkb, Wlb, Wrb);
    k_gate<<<dim3(Bb * Nn), 256, 0, stream>>>(x, adj, Wd, bd, xg);
    k_transpose<<<dim3(Dd / 64, Nn / 64, Bb), 256, 0, stream>>>(xg, xgT);
    k_qk_gemm<<<dim3(Dd / 128, (Bb * Nn) / 128), 256, 0, stream>>>(xg, Wqkb, bqk, QK);
    k_s_gemm<<<dim3(136, Bb), 256, 0, stream>>>(QK, adj, S, denom);
    k_h_gemm<<<dim3(512), 256, 0, stream>>>(S, xgT, denom, h);
    k_out_gemm<<<dim3(Dd / 128, (Bb * Nn) / 128), 256, 0, stream>>>(h, xg, Wlb, Wrb, bl, out);
}